// Round 1
// baseline (466.568 us; speedup 1.0000x reference)
//
#include <hip/hip_runtime.h>
#include <hip/hip_bf16.h>
#include <hip/hip_fp16.h>
#include <math.h>

#define NN 50000
#define EE 800000
#define E2K 400000
#define DINK 512
#define DHK 128
#define CK 8
#define KIT 5
#define NBLKS 196  // ceil(NN/256)
#define NPB 32     // nodes per bp_iter block
#define CAP 1024   // LDS message cache (edges); block edge-count mean ~512

typedef __attribute__((ext_vector_type(8))) short short8;
typedef __attribute__((ext_vector_type(4))) float f32x4;

__device__ __forceinline__ unsigned short f2bf(float f) {
    union { float f; unsigned int u; } v;
    v.f = f;
    unsigned int u = v.u;
    unsigned int r = (u + 0x7FFFu + ((u >> 16) & 1u)) >> 16;  // RNE
    return (unsigned short)r;
}
__device__ __forceinline__ float bfu2f(unsigned int lo16) {
    union { unsigned int u; float f; } v;
    v.u = lo16 << 16;
    return v.f;
}

// merged prep: blocks 0..255 transpose W1 -> bf16 W1t; block 256 computes logH
__global__ __launch_bounds__(256) void prep_kernel(
    const float* __restrict__ W1, const float* __restrict__ param,
    unsigned short* __restrict__ W1t, float* __restrict__ logH) {
    if (blockIdx.x < 256) {
        int idx = blockIdx.x * 256 + threadIdx.x;  // 65536
        int n = idx >> 9;
        int k = idx & 511;
        W1t[idx] = f2bf(W1[(size_t)k * DHK + n]);
    } else if (threadIdx.x < 64) {
        int t = threadIdx.x;
        int i = t >> 3, j = t & 7;
        float z = param[i * 8 + j] + param[j * 8 + i];
        logH[t] = fminf(z, 0.0f) - log1pf(expf(-fabsf(z)));
    }
}

// MFMA MLP: 64 rows/block -> grid 782 (~3 blocks/CU, 12 waves/CU) to fix the
// latency-bound underfill seen at 128 rows/block (grid 391, occupancy 15%).
// Wave layout: 2x2 waves over the 64x128 output; each wave owns 32x64.
__global__ __launch_bounds__(256) void mlp_mfma_kernel(
    const float* __restrict__ x, const unsigned short* __restrict__ W1t,
    const float* __restrict__ b1, const float* __restrict__ W2,
    const float* __restrict__ b2, float* __restrict__ logb0) {
    __shared__ unsigned short hs[64 * 136];
    __shared__ float W2s[128 * 8];
    __shared__ float b1s[128];
    __shared__ float b2s[8];

    const int tid = threadIdx.x;
    const int wave = tid >> 6;
    const int lane = tid & 63;
    const int q = lane >> 4;
    const int lm = lane & 15;
    const int wm = wave >> 1, wn = wave & 1;
    const int n0 = blockIdx.x * 64;

    if (tid < 128) b1s[tid] = b1[tid];
    if (tid < 8) b2s[tid] = b2[tid];
    {
        int i = tid * 4;
        *(float4*)&W2s[i] = *(const float4*)&W2[i];
    }
    __syncthreads();

    const float* xptr[2];
#pragma unroll
    for (int mt = 0; mt < 2; ++mt) {
        int r = n0 + wm * 32 + mt * 16 + lm;
        if (r > NN - 1) r = NN - 1;
        xptr[mt] = x + (size_t)r * DINK + q * 8;
    }
    const unsigned short* bptr[4];
#pragma unroll
    for (int nt = 0; nt < 4; ++nt) {
        int c = wn * 64 + nt * 16 + lm;
        bptr[nt] = W1t + (size_t)c * DINK + q * 8;
    }

    f32x4 acc[2][4];
#pragma unroll
    for (int mt = 0; mt < 2; ++mt)
#pragma unroll
        for (int nt = 0; nt < 4; ++nt) acc[mt][nt] = (f32x4){0.f, 0.f, 0.f, 0.f};

    float4 ar[2][2];
    short8 bc[4];
#pragma unroll
    for (int mt = 0; mt < 2; ++mt) {
        ar[mt][0] = *(const float4*)(xptr[mt]);
        ar[mt][1] = *(const float4*)(xptr[mt] + 4);
    }
#pragma unroll
    for (int nt = 0; nt < 4; ++nt) bc[nt] = *(const short8*)(bptr[nt]);

#pragma unroll
    for (int k0 = 32; k0 <= DINK; k0 += 32) {
        float4 ar2[2][2];
        short8 b2f[4];
        if (k0 < DINK) {
#pragma unroll
            for (int mt = 0; mt < 2; ++mt) {
                ar2[mt][0] = *(const float4*)(xptr[mt] + k0);
                ar2[mt][1] = *(const float4*)(xptr[mt] + k0 + 4);
            }
#pragma unroll
            for (int nt = 0; nt < 4; ++nt)
                b2f[nt] = *(const short8*)(bptr[nt] + k0);
        }
        short8 af[2];
#pragma unroll
        for (int mt = 0; mt < 2; ++mt) {
            union { short8 s; __hip_bfloat162 h[4]; } cv;
            cv.h[0] = __float22bfloat162_rn(make_float2(ar[mt][0].x, ar[mt][0].y));
            cv.h[1] = __float22bfloat162_rn(make_float2(ar[mt][0].z, ar[mt][0].w));
            cv.h[2] = __float22bfloat162_rn(make_float2(ar[mt][1].x, ar[mt][1].y));
            cv.h[3] = __float22bfloat162_rn(make_float2(ar[mt][1].z, ar[mt][1].w));
            af[mt] = cv.s;
        }
#pragma unroll
        for (int mt = 0; mt < 2; ++mt)
#pragma unroll
            for (int nt = 0; nt < 4; ++nt)
                acc[mt][nt] = __builtin_amdgcn_mfma_f32_16x16x32_bf16(
                    af[mt], bc[nt], acc[mt][nt], 0, 0, 0);
        if (k0 < DINK) {
#pragma unroll
            for (int mt = 0; mt < 2; ++mt) {
                ar[mt][0] = ar2[mt][0];
                ar[mt][1] = ar2[mt][1];
            }
#pragma unroll
            for (int nt = 0; nt < 4; ++nt) bc[nt] = b2f[nt];
        }
    }

#pragma unroll
    for (int nt = 0; nt < 4; ++nt) {
        int j = wn * 64 + nt * 16 + lm;
        float bj = b1s[j];
#pragma unroll
        for (int mt = 0; mt < 2; ++mt) {
            int rbase = wm * 32 + mt * 16 + q * 4;
#pragma unroll
            for (int r = 0; r < 4; ++r) {
                float h = fmaxf(acc[mt][nt][r] + bj, 0.0f);
                hs[(rbase + r) * 136 + j] = f2bf(h);
            }
        }
    }
    __syncthreads();

    // phase 2: 4 threads per row, 32 cols each
    int row = tid >> 2;
    int qh = tid & 3;
    const unsigned short* hp = &hs[row * 136 + qh * 32];
    float p[8] = {0.f, 0.f, 0.f, 0.f, 0.f, 0.f, 0.f, 0.f};
#pragma unroll
    for (int ch = 0; ch < 4; ++ch) {
        uint4 c4 = *(const uint4*)(hp + ch * 8);
        unsigned int uu[4] = {c4.x, c4.y, c4.z, c4.w};
#pragma unroll
        for (int p2 = 0; p2 < 4; ++p2) {
            float h0 = bfu2f(uu[p2] & 0xFFFFu);
            float h1 = bfu2f(uu[p2] >> 16);
            int j = qh * 32 + ch * 8 + p2 * 2;
            const float* w0 = &W2s[j * 8];
            const float* w1 = &W2s[(j + 1) * 8];
#pragma unroll
            for (int c = 0; c < 8; ++c) p[c] = fmaf(h0, w0[c], p[c]);
#pragma unroll
            for (int c = 0; c < 8; ++c) p[c] = fmaf(h1, w1[c], p[c]);
        }
    }
#pragma unroll
    for (int c = 0; c < 8; ++c) p[c] += __shfl_xor(p[c], 1, 64);
#pragma unroll
    for (int c = 0; c < 8; ++c) p[c] += __shfl_xor(p[c], 2, 64);
    int grow = n0 + row;
    if (qh == 0 && grow < NN) {
        float v[8];
        float mx = -1e30f;
#pragma unroll
        for (int c = 0; c < 8; ++c) {
            v[c] = p[c] + b2s[c];
            mx = fmaxf(mx, v[c]);
        }
        float s = 0.0f;
#pragma unroll
        for (int c = 0; c < 8; ++c) s += expf(v[c] - mx);
        float ln = mx + logf(s);
        float4* p0 = (float4*)&logb0[(size_t)grow * 8];
        p0[0] = make_float4(v[0] - ln, v[1] - ln, v[2] - ln, v[3] - ln);
        p0[1] = make_float4(v[4] - ln, v[5] - ln, v[6] - ln, v[7] - ln);
    }
}

// ---------------- CSR setup (paired: one thread per UNDIRECTED edge) --------

__global__ __launch_bounds__(256) void deg_pair_kernel(const int* __restrict__ ei,
                                                       int* __restrict__ cnt) {
    int e = blockIdx.x * 256 + threadIdx.x;
    if (e >= E2K) return;
    int s = ei[e];
    int d = ei[EE + e];
    atomicAdd(&cnt[d], 1);
    atomicAdd(&cnt[s], 1);
}

__global__ __launch_bounds__(256) void scan_partial_kernel(
    const int* __restrict__ cnt, int* __restrict__ partial) {
    __shared__ int sd[256];
    int t = threadIdx.x;
    int i = blockIdx.x * 256 + t;
    sd[t] = (i < NN) ? cnt[i] : 0;
    __syncthreads();
#pragma unroll
    for (int s = 128; s > 0; s >>= 1) {
        if (t < s) sd[t] += sd[t + s];
        __syncthreads();
    }
    if (t == 0) partial[blockIdx.x] = sd[0];
}

__global__ __launch_bounds__(256) void scan_tops_kernel(
    const int* __restrict__ partial, int* __restrict__ tops) {
    __shared__ int sd[256];
    int t = threadIdx.x;
    sd[t] = (t < NBLKS) ? partial[t] : 0;
    __syncthreads();
#pragma unroll
    for (int s = 1; s < 256; s <<= 1) {
        int a = sd[t];
        int b = (t >= s) ? sd[t - s] : 0;
        __syncthreads();
        sd[t] = a + b;
        __syncthreads();
    }
    if (t < NBLKS) tops[t] = (t > 0) ? sd[t - 1] : 0;
}

__global__ __launch_bounds__(256) void scan_write_kernel(
    const int* __restrict__ cnt, const int* __restrict__ tops,
    int* __restrict__ off) {
    __shared__ int sd[256];
    int t = threadIdx.x;
    int i = blockIdx.x * 256 + t;
    int v = (i < NN) ? cnt[i] : 0;
    sd[t] = v;
    __syncthreads();
#pragma unroll
    for (int s = 1; s < 256; s <<= 1) {
        int a = sd[t];
        int b = (t >= s) ? sd[t - s] : 0;
        __syncthreads();
        sd[t] = a + b;
        __syncthreads();
    }
    if (i < NN) off[i] = tops[blockIdx.x] + sd[t] - v;
    if (i == NN - 1) off[NN] = EE;
}

// packed stores: perm_sw=(src,wbits), perm_dr=(dst,rvp) — 4 random 8B stores
// per undirected edge
__global__ __launch_bounds__(256) void pos_pair_kernel(
    const int* __restrict__ ei, const float* __restrict__ ew,
    const int* __restrict__ off, int* __restrict__ cnt,
    int2* __restrict__ perm_sw, int2* __restrict__ perm_dr) {
    int e = blockIdx.x * 256 + threadIdx.x;
    if (e >= E2K) return;
    int s = ei[e];
    int d = ei[EE + e];
    int wbits = __float_as_int(ew[e]);
    int pA = off[d] + atomicAdd(&cnt[d], 1);  // edge e: s->d
    int pB = off[s] + atomicAdd(&cnt[s], 1);  // edge e+E2: d->s
    int2 v;
    v.x = s; v.y = wbits; perm_sw[pA] = v;
    v.x = d;              perm_sw[pB] = v;
    v.x = d; v.y = pB;    perm_dr[pA] = v;
    v.x = s; v.y = pA;    perm_dr[pB] = v;
}

// ---------------- fused BP iteration (GATHER form): one dispatch per iter ---
// xin[k] = belief[src(k)] - msg_prev[rv(k)], gathered on the fly:
//   belief[src] : random 32B reads in a 1.6MB fp32 array  -> L2-resident
//   msg_prev[rv]: random 16B reads in a 12.8MB fp16 array -> L2/L3, read-only
// Messages are written CONTIGUOUSLY (msg_next[j], coalesced 16B stores) and
// beliefs densely (bel_next[n*8+c], coalesced 4B stores). This removes the
// previous scatter pass entirely (6.4M random 2B stores + extra edge walk).
__global__ __launch_bounds__(256) void bp_iter_kernel(
    const float* __restrict__ logb0, const int* __restrict__ off,
    const int2* __restrict__ perm_sw, const int2* __restrict__ perm_dr,
    const float* __restrict__ logH, const uint4* __restrict__ msg_prev,
    uint4* __restrict__ msg_next, const float* __restrict__ bel_prev,
    float* __restrict__ bel_next, float* __restrict__ out,
    int first, int last) {
    __shared__ _Float16 smg[CAP * 8];  // 16 KB message cache
    __shared__ float lH[64];
    const int t = threadIdx.x;
    if (t < 64) lH[t] = logH[t];

    const int n0 = blockIdx.x * NPB;
    const int nend = (n0 + NPB < NN) ? (n0 + NPB) : NN;
    const int jb0 = off[n0];
    const int jb1 = off[nend];
    const int nl = t >> 3;
    const int c = t & 7;
    const int n = n0 + nl;

    float a = 0.0f;
    int jn0 = 0, jn1 = 0;
    if (n < nend) {
        jn0 = off[n];
        jn1 = off[n + 1];
        a = logb0[(size_t)n * 8 + c];
    }
    __syncthreads();  // lH ready

    for (int cb = jb0; cb < jb1; cb += CAP) {
        int ce = (cb + CAP < jb1) ? (cb + CAP) : jb1;
        for (int j = cb + t; j < ce; j += 256) {
            int2 sw = perm_sw[j];
            float w = __int_as_float(sw.y);
            const float4* pb = (const float4*)&bel_prev[(size_t)sw.x * 8];
            float4 v0 = pb[0], v1 = pb[1];
            float xj[8];
            xj[0] = v0.x; xj[1] = v0.y; xj[2] = v0.z; xj[3] = v0.w;
            xj[4] = v1.x; xj[5] = v1.y; xj[6] = v1.z; xj[7] = v1.w;
            if (!first) {
                int rvp = perm_dr[j].y;
                union { uint4 u; _Float16 h[8]; } mv;
                mv.u = msg_prev[rvp];
#pragma unroll
                for (int k = 0; k < 8; ++k) xj[k] -= (float)mv.h[k];
            }
            float M = xj[0];
#pragma unroll
            for (int k = 1; k < 8; ++k) M = fmaxf(M, xj[k]);
#pragma unroll
            for (int k = 0; k < 8; ++k) xj[k] -= M;
            float mg[8];
#pragma unroll
            for (int c2 = 0; c2 < 8; ++c2) {
                float ssum = 0.0f;
#pragma unroll
                for (int c1 = 0; c1 < 8; ++c1)
                    ssum += __expf(fmaf(w, lH[c1 * 8 + c2], xj[c1]));
                mg[c2] = __logf(ssum);
            }
            float mm = mg[0];
#pragma unroll
            for (int k = 1; k < 8; ++k) mm = fmaxf(mm, mg[k]);
            float se = 0.0f;
#pragma unroll
            for (int k = 0; k < 8; ++k) se += __expf(mg[k] - mm);
            float ln = mm + __logf(se);
            union { uint4 u; _Float16 h[8]; } ov;
#pragma unroll
            for (int k = 0; k < 8; ++k) ov.h[k] = (_Float16)(mg[k] - ln);
            *(uint4*)&smg[(j - cb) * 8] = ov.u;
            if (!last) msg_next[j] = ov.u;  // contiguous, coalesced
        }
        __syncthreads();
        // aggregate this chunk's contribution for my node
        int lo = (jn0 > cb) ? jn0 : cb;
        int hi = (jn1 < ce) ? jn1 : ce;
        for (int j = lo; j < hi; ++j) a += (float)smg[(j - cb) * 8 + c];
        __syncthreads();  // protect smg before next chunk
    }

    // ---- normalize belief (8-thread groups) ----
    float mx = a;
#pragma unroll
    for (int s = 1; s < 8; s <<= 1) mx = fmaxf(mx, __shfl_xor(mx, s, 8));
    float sum = __expf(a - mx);
#pragma unroll
    for (int s = 1; s < 8; s <<= 1) sum += __shfl_xor(sum, s, 8);
    float v = a - (mx + __logf(sum));
    if (n < nend) {
        if (last) out[(size_t)n * 8 + c] = v;
        else bel_next[(size_t)n * 8 + c] = v;  // dense fp32, coalesced
    }
}

extern "C" void kernel_launch(void* const* d_in, const int* in_sizes, int n_in,
                              void* d_out, int out_size, void* d_ws, size_t ws_size,
                              hipStream_t stream) {
    const float* x = (const float*)d_in[0];
    const int* ei = (const int*)d_in[1];
    const float* ew = (const float*)d_in[2];
    const float* W1 = (const float*)d_in[4];
    const float* b1 = (const float*)d_in[5];
    const float* W2 = (const float*)d_in[6];
    const float* b2 = (const float*)d_in[7];
    const float* param = (const float*)d_in[8];
    float* out = (float*)d_out;

    float* wsf = (float*)d_ws;
    float* logH = wsf;                               // 64 f
    float* logb0 = logH + 64;                        // 400000 f
    uint4* msgA = (uint4*)(logb0 + (size_t)NN * 8);  // 12.8 MB
    uint4* msgB = msgA + EE;                         // 12.8 MB
    int* off = (int*)(msgB + EE);                    // padded to 50004 ints
    int2* perm_sw = (int2*)(off + 50004);            // 800000 int2
    int2* perm_dr = perm_sw + EE;                    // 800000 int2
    unsigned short* W1t = (unsigned short*)(perm_dr + EE);  // 65536 bf16
    float* belA = (float*)(W1t + 65536);             // 400000 f (16B aligned)
    float* belB = belA + (size_t)NN * 8;             // 400000 f
    // setup-only scratch aliases msgA (first written at iter 0, after setup)
    int* cnt = (int*)msgA;                           // 50000
    int* partial = cnt + NN;                         // 196
    int* tops = partial + NBLKS;                     // 196

    prep_kernel<<<257, 256, 0, stream>>>(W1, param, W1t, logH);
    mlp_mfma_kernel<<<(NN + 63) / 64, 256, 0, stream>>>(x, W1t, b1, W2, b2,
                                                        logb0);

    const int E2B = (E2K + 255) / 256;

    hipMemsetAsync(cnt, 0, (size_t)NN * sizeof(int), stream);
    deg_pair_kernel<<<E2B, 256, 0, stream>>>(ei, cnt);
    scan_partial_kernel<<<NBLKS, 256, 0, stream>>>(cnt, partial);
    scan_tops_kernel<<<1, 256, 0, stream>>>(partial, tops);
    scan_write_kernel<<<NBLKS, 256, 0, stream>>>(cnt, tops, off);
    hipMemsetAsync(cnt, 0, (size_t)NN * sizeof(int), stream);
    pos_pair_kernel<<<E2B, 256, 0, stream>>>(ei, ew, off, cnt, perm_sw, perm_dr);

    const int NB = (NN + NPB - 1) / NPB;
    uint4* msgs[2] = {msgA, msgB};
    float* bels[2] = {belA, belB};
    const float* bprev = logb0;
    for (int it = 0; it < KIT; ++it) {
        bp_iter_kernel<<<NB, 256, 0, stream>>>(
            logb0, off, perm_sw, perm_dr, logH,
            msgs[(it + 1) & 1] /*prev*/, msgs[it & 1] /*next*/,
            bprev, bels[it & 1], out,
            it == 0 ? 1 : 0, it == KIT - 1 ? 1 : 0);
        bprev = bels[it & 1];
    }
}

// Round 2
// 463.403 us; speedup vs baseline: 1.0068x; 1.0068x over previous
//
#include <hip/hip_runtime.h>
#include <hip/hip_bf16.h>
#include <hip/hip_fp16.h>
#include <math.h>

#define NN 50000
#define EE 800000
#define E2K 400000
#define DINK 512
#define DHK 128
#define CK 8
#define KIT 5
#define NBLKS 196  // ceil(NN/256)

typedef __attribute__((ext_vector_type(8))) short short8;
typedef __attribute__((ext_vector_type(4))) float f32x4;

__device__ __forceinline__ unsigned short f2bf(float f) {
    union { float f; unsigned int u; } v;
    v.f = f;
    unsigned int u = v.u;
    unsigned int r = (u + 0x7FFFu + ((u >> 16) & 1u)) >> 16;  // RNE
    return (unsigned short)r;
}
__device__ __forceinline__ float bfu2f(unsigned int lo16) {
    union { unsigned int u; float f; } v;
    v.u = lo16 << 16;
    return v.f;
}

// merged prep: blocks 0..255 transpose W1 -> bf16 W1t; block 256 computes logH
__global__ __launch_bounds__(256) void prep_kernel(
    const float* __restrict__ W1, const float* __restrict__ param,
    unsigned short* __restrict__ W1t, float* __restrict__ logH) {
    if (blockIdx.x < 256) {
        int idx = blockIdx.x * 256 + threadIdx.x;  // 65536
        int n = idx >> 9;
        int k = idx & 511;
        W1t[idx] = f2bf(W1[(size_t)k * DHK + n]);
    } else if (threadIdx.x < 64) {
        int t = threadIdx.x;
        int i = t >> 3, j = t & 7;
        float z = param[i * 8 + j] + param[j * 8 + i];
        logH[t] = fminf(z, 0.0f) - log1pf(expf(-fabsf(z)));
    }
}

// MFMA MLP (R7-proven: 256 thr, 128 rows/block, VGPR ~100, ~70us). Round-1's
// 64-row variant regressed (same x-bytes in flight, 2x W1t traffic, 3x bank
// conflicts) — keep this version verbatim.
__global__ __launch_bounds__(256) void mlp_mfma_kernel(
    const float* __restrict__ x, const unsigned short* __restrict__ W1t,
    const float* __restrict__ b1, const float* __restrict__ W2,
    const float* __restrict__ b2, float* __restrict__ logb0) {
    __shared__ unsigned short hs[128 * 136];
    __shared__ float W2s[128 * 8];
    __shared__ float b1s[128];
    __shared__ float b2s[8];

    const int tid = threadIdx.x;
    const int wave = tid >> 6;
    const int lane = tid & 63;
    const int q = lane >> 4;
    const int lm = lane & 15;
    const int wm = wave >> 1, wn = wave & 1;
    const int n0 = blockIdx.x * 128;

    if (tid < 128) b1s[tid] = b1[tid];
    if (tid < 8) b2s[tid] = b2[tid];
    {
        int i = tid * 4;
        *(float4*)&W2s[i] = *(const float4*)&W2[i];
    }
    __syncthreads();

    const float* xptr[4];
#pragma unroll
    for (int mt = 0; mt < 4; ++mt) {
        int r = n0 + wm * 64 + mt * 16 + lm;
        if (r > NN - 1) r = NN - 1;
        xptr[mt] = x + (size_t)r * DINK + q * 8;
    }
    const unsigned short* bptr[4];
#pragma unroll
    for (int nt = 0; nt < 4; ++nt) {
        int c = wn * 64 + nt * 16 + lm;
        bptr[nt] = W1t + (size_t)c * DINK + q * 8;
    }

    f32x4 acc[4][4];
#pragma unroll
    for (int mt = 0; mt < 4; ++mt)
#pragma unroll
        for (int nt = 0; nt < 4; ++nt) acc[mt][nt] = (f32x4){0.f, 0.f, 0.f, 0.f};

    float4 ar[4][2];
    short8 bc[4];
#pragma unroll
    for (int mt = 0; mt < 4; ++mt) {
        ar[mt][0] = *(const float4*)(xptr[mt]);
        ar[mt][1] = *(const float4*)(xptr[mt] + 4);
    }
#pragma unroll
    for (int nt = 0; nt < 4; ++nt) bc[nt] = *(const short8*)(bptr[nt]);

#pragma unroll
    for (int k0 = 32; k0 <= DINK; k0 += 32) {
        float4 ar2[4][2];
        short8 b2f[4];
        if (k0 < DINK) {
#pragma unroll
            for (int mt = 0; mt < 4; ++mt) {
                ar2[mt][0] = *(const float4*)(xptr[mt] + k0);
                ar2[mt][1] = *(const float4*)(xptr[mt] + k0 + 4);
            }
#pragma unroll
            for (int nt = 0; nt < 4; ++nt)
                b2f[nt] = *(const short8*)(bptr[nt] + k0);
        }
        short8 af[4];
#pragma unroll
        for (int mt = 0; mt < 4; ++mt) {
            union { short8 s; __hip_bfloat162 h[4]; } cv;
            cv.h[0] = __float22bfloat162_rn(make_float2(ar[mt][0].x, ar[mt][0].y));
            cv.h[1] = __float22bfloat162_rn(make_float2(ar[mt][0].z, ar[mt][0].w));
            cv.h[2] = __float22bfloat162_rn(make_float2(ar[mt][1].x, ar[mt][1].y));
            cv.h[3] = __float22bfloat162_rn(make_float2(ar[mt][1].z, ar[mt][1].w));
            af[mt] = cv.s;
        }
#pragma unroll
        for (int mt = 0; mt < 4; ++mt)
#pragma unroll
            for (int nt = 0; nt < 4; ++nt)
                acc[mt][nt] = __builtin_amdgcn_mfma_f32_16x16x32_bf16(
                    af[mt], bc[nt], acc[mt][nt], 0, 0, 0);
        if (k0 < DINK) {
#pragma unroll
            for (int mt = 0; mt < 4; ++mt) {
                ar[mt][0] = ar2[mt][0];
                ar[mt][1] = ar2[mt][1];
            }
#pragma unroll
            for (int nt = 0; nt < 4; ++nt) bc[nt] = b2f[nt];
        }
    }

#pragma unroll
    for (int nt = 0; nt < 4; ++nt) {
        int j = wn * 64 + nt * 16 + lm;
        float bj = b1s[j];
#pragma unroll
        for (int mt = 0; mt < 4; ++mt) {
            int rbase = wm * 64 + mt * 16 + q * 4;
#pragma unroll
            for (int r = 0; r < 4; ++r) {
                float h = fmaxf(acc[mt][nt][r] + bj, 0.0f);
                hs[(rbase + r) * 136 + j] = f2bf(h);
            }
        }
    }
    __syncthreads();

    int row = tid >> 1;
    int half = tid & 1;
    const unsigned short* hp = &hs[row * 136 + half * 64];
    float p[8] = {0.f, 0.f, 0.f, 0.f, 0.f, 0.f, 0.f, 0.f};
#pragma unroll
    for (int ch = 0; ch < 8; ++ch) {
        uint4 c4 = *(const uint4*)(hp + ch * 8);
        unsigned int uu[4] = {c4.x, c4.y, c4.z, c4.w};
#pragma unroll
        for (int p2 = 0; p2 < 4; ++p2) {
            float h0 = bfu2f(uu[p2] & 0xFFFFu);
            float h1 = bfu2f(uu[p2] >> 16);
            int j = half * 64 + ch * 8 + p2 * 2;
            const float* w0 = &W2s[j * 8];
            const float* w1 = &W2s[(j + 1) * 8];
#pragma unroll
            for (int c = 0; c < 8; ++c) p[c] = fmaf(h0, w0[c], p[c]);
#pragma unroll
            for (int c = 0; c < 8; ++c) p[c] = fmaf(h1, w1[c], p[c]);
        }
    }
#pragma unroll
    for (int c = 0; c < 8; ++c) p[c] += __shfl_xor(p[c], 1, 64);
    int grow = n0 + row;
    if (half == 0 && grow < NN) {
        float v[8];
        float mx = -1e30f;
#pragma unroll
        for (int c = 0; c < 8; ++c) {
            v[c] = p[c] + b2s[c];
            mx = fmaxf(mx, v[c]);
        }
        float s = 0.0f;
#pragma unroll
        for (int c = 0; c < 8; ++c) s += expf(v[c] - mx);
        float ln = mx + logf(s);
        float4* p0 = (float4*)&logb0[(size_t)grow * 8];
        p0[0] = make_float4(v[0] - ln, v[1] - ln, v[2] - ln, v[3] - ln);
        p0[1] = make_float4(v[4] - ln, v[5] - ln, v[6] - ln, v[7] - ln);
    }
}

// ---------------- CSR setup (paired: one thread per UNDIRECTED edge) --------

__global__ __launch_bounds__(256) void deg_pair_kernel(const int* __restrict__ ei,
                                                       int* __restrict__ cnt) {
    int e = blockIdx.x * 256 + threadIdx.x;
    if (e >= E2K) return;
    int s = ei[e];
    int d = ei[EE + e];
    atomicAdd(&cnt[d], 1);
    atomicAdd(&cnt[s], 1);
}

__global__ __launch_bounds__(256) void scan_partial_kernel(
    const int* __restrict__ cnt, int* __restrict__ partial) {
    __shared__ int sd[256];
    int t = threadIdx.x;
    int i = blockIdx.x * 256 + t;
    sd[t] = (i < NN) ? cnt[i] : 0;
    __syncthreads();
#pragma unroll
    for (int s = 128; s > 0; s >>= 1) {
        if (t < s) sd[t] += sd[t + s];
        __syncthreads();
    }
    if (t == 0) partial[blockIdx.x] = sd[0];
}

__global__ __launch_bounds__(256) void scan_tops_kernel(
    const int* __restrict__ partial, int* __restrict__ tops) {
    __shared__ int sd[256];
    int t = threadIdx.x;
    sd[t] = (t < NBLKS) ? partial[t] : 0;
    __syncthreads();
#pragma unroll
    for (int s = 1; s < 256; s <<= 1) {
        int a = sd[t];
        int b = (t >= s) ? sd[t - s] : 0;
        __syncthreads();
        sd[t] = a + b;
        __syncthreads();
    }
    if (t < NBLKS) tops[t] = (t > 0) ? sd[t - 1] : 0;
}

__global__ __launch_bounds__(256) void scan_write_kernel(
    const int* __restrict__ cnt, const int* __restrict__ tops,
    int* __restrict__ off) {
    __shared__ int sd[256];
    int t = threadIdx.x;
    int i = blockIdx.x * 256 + t;
    int v = (i < NN) ? cnt[i] : 0;
    sd[t] = v;
    __syncthreads();
#pragma unroll
    for (int s = 1; s < 256; s <<= 1) {
        int a = sd[t];
        int b = (t >= s) ? sd[t - s] : 0;
        __syncthreads();
        sd[t] = a + b;
        __syncthreads();
    }
    if (i < NN) off[i] = tops[blockIdx.x] + sd[t] - v;
    if (i == NN - 1) off[NN] = EE;
}

// perm_sw=(src,wbits) int2; rvp = permuted index of reverse edge (int).
__global__ __launch_bounds__(256) void pos_pair_kernel(
    const int* __restrict__ ei, const float* __restrict__ ew,
    const int* __restrict__ off, int* __restrict__ cnt,
    int2* __restrict__ perm_sw, int* __restrict__ rvp) {
    int e = blockIdx.x * 256 + threadIdx.x;
    if (e >= E2K) return;
    int s = ei[e];
    int d = ei[EE + e];
    int wbits = __float_as_int(ew[e]);
    int pA = off[d] + atomicAdd(&cnt[d], 1);  // edge e: s->d
    int pB = off[s] + atomicAdd(&cnt[s], 1);  // edge e+E2: d->s
    int2 v;
    v.x = s; v.y = wbits; perm_sw[pA] = v;
    v.x = d;              perm_sw[pB] = v;
    rvp[pA] = pB;
    rvp[pB] = pA;
}

// ---------------- BP iteration, split into two barrier-free kernels --------
// msg_kernel: edge-parallel, 2 edges/thread, all gathers issued up front.
//   xin = bel_prev[src] - msg_prev[rvp];  msg = lognorm(LSE_c1(xin + w*logH))
//   written CONTIGUOUSLY to msg_next[j] (fp16x8 = 16B).
// agg_kernel: node-parallel (8 lanes/node), sums the node's contiguous CSR
//   slice of msg_next, normalizes with logb0, writes belief (or out).
// No workgroup barriers anywhere in the hot path -> waves free-run, gather
// latency hidden by ~24 waves/CU instead of block-lockstep phases.
__global__ __launch_bounds__(256) void msg_kernel(
    const int2* __restrict__ perm_sw, const int* __restrict__ rvp,
    const float* __restrict__ logH, const uint4* __restrict__ msg_prev,
    const float* __restrict__ bel_prev, uint4* __restrict__ msg_next,
    int first) {
    __shared__ float lH[64];
    const int t = threadIdx.x;
    if (t < 64) lH[t] = logH[t];
    __syncthreads();

    const int base = blockIdx.x * 512 + t;
    int jj[2];
    int2 sw[2];
#pragma unroll
    for (int e = 0; e < 2; ++e) {
        int j = base + e * 256;
        jj[e] = j;
        int jc = (j < EE) ? j : (EE - 1);
        sw[e] = perm_sw[jc];
    }
    float4 ba[2], bb[2];
#pragma unroll
    for (int e = 0; e < 2; ++e) {
        const float4* pb = (const float4*)&bel_prev[(size_t)sw[e].x * 8];
        ba[e] = pb[0];
        bb[e] = pb[1];
    }
    uint4 mp[2];
    if (!first) {
        int rv[2];
#pragma unroll
        for (int e = 0; e < 2; ++e) {
            int j = jj[e];
            int jc = (j < EE) ? j : (EE - 1);
            rv[e] = rvp[jc];
        }
#pragma unroll
        for (int e = 0; e < 2; ++e) mp[e] = msg_prev[rv[e]];
    }

#pragma unroll
    for (int e = 0; e < 2; ++e) {
        float w = __int_as_float(sw[e].y);
        float xj[8];
        xj[0] = ba[e].x; xj[1] = ba[e].y; xj[2] = ba[e].z; xj[3] = ba[e].w;
        xj[4] = bb[e].x; xj[5] = bb[e].y; xj[6] = bb[e].z; xj[7] = bb[e].w;
        if (!first) {
            union { uint4 u; _Float16 h[8]; } cv;
            cv.u = mp[e];
#pragma unroll
            for (int k = 0; k < 8; ++k) xj[k] -= (float)cv.h[k];
        }
        float M = xj[0];
#pragma unroll
        for (int k = 1; k < 8; ++k) M = fmaxf(M, xj[k]);
#pragma unroll
        for (int k = 0; k < 8; ++k) xj[k] -= M;
        float mg[8];
#pragma unroll
        for (int c2 = 0; c2 < 8; ++c2) {
            float ssum = 0.0f;
#pragma unroll
            for (int c1 = 0; c1 < 8; ++c1)
                ssum += __expf(fmaf(w, lH[c1 * 8 + c2], xj[c1]));
            mg[c2] = __logf(ssum);
        }
        float mm = mg[0];
#pragma unroll
        for (int k = 1; k < 8; ++k) mm = fmaxf(mm, mg[k]);
        float se = 0.0f;
#pragma unroll
        for (int k = 0; k < 8; ++k) se += __expf(mg[k] - mm);
        float ln = mm + __logf(se);
        union { uint4 u; _Float16 h[8]; } ov;
#pragma unroll
        for (int k = 0; k < 8; ++k) ov.h[k] = (_Float16)(mg[k] - ln);
        if (jj[e] < EE) msg_next[jj[e]] = ov.u;
    }
}

__global__ __launch_bounds__(256) void agg_kernel(
    const float* __restrict__ logb0, const int* __restrict__ off,
    const uint4* __restrict__ msg, float* __restrict__ bel_next,
    float* __restrict__ out, int last) {
    const int t = threadIdx.x;
    const int n = blockIdx.x * 32 + (t >> 3);
    const int c = t & 7;
    if (n >= NN) return;
    float a = logb0[(size_t)n * 8 + c];
    const int j0 = off[n];
    const int j1 = off[n + 1];
    const _Float16* mh = (const _Float16*)msg;
    for (int j = j0; j < j1; ++j) a += (float)mh[(size_t)j * 8 + c];
    float mx = a;
#pragma unroll
    for (int s = 1; s < 8; s <<= 1) mx = fmaxf(mx, __shfl_xor(mx, s, 8));
    float sum = __expf(a - mx);
#pragma unroll
    for (int s = 1; s < 8; s <<= 1) sum += __shfl_xor(sum, s, 8);
    float v = a - (mx + __logf(sum));
    if (last) out[(size_t)n * 8 + c] = v;
    else bel_next[(size_t)n * 8 + c] = v;
}

extern "C" void kernel_launch(void* const* d_in, const int* in_sizes, int n_in,
                              void* d_out, int out_size, void* d_ws, size_t ws_size,
                              hipStream_t stream) {
    const float* x = (const float*)d_in[0];
    const int* ei = (const int*)d_in[1];
    const float* ew = (const float*)d_in[2];
    const float* W1 = (const float*)d_in[4];
    const float* b1 = (const float*)d_in[5];
    const float* W2 = (const float*)d_in[6];
    const float* b2 = (const float*)d_in[7];
    const float* param = (const float*)d_in[8];
    float* out = (float*)d_out;

    float* wsf = (float*)d_ws;
    float* logH = wsf;                               // 64 f
    float* logb0 = logH + 64;                        // 400000 f
    uint4* msgA = (uint4*)(logb0 + (size_t)NN * 8);  // 12.8 MB
    uint4* msgB = msgA + EE;                         // 12.8 MB
    int* off = (int*)(msgB + EE);                    // padded to 50004 ints
    int2* perm_sw = (int2*)(off + 50004);            // 800000 int2
    int* rvp = (int*)(perm_sw + EE);                 // 800000 int
    unsigned short* W1t = (unsigned short*)(rvp + EE);  // 65536 bf16
    float* belA = (float*)(W1t + 65536);             // 400000 f (16B aligned)
    float* belB = belA + (size_t)NN * 8;             // 400000 f
    // setup-only scratch aliases msgA (first written by msg_kernel iter 0)
    int* cnt = (int*)msgA;                           // 50000
    int* partial = cnt + NN;                         // 196
    int* tops = partial + NBLKS;                     // 196

    prep_kernel<<<257, 256, 0, stream>>>(W1, param, W1t, logH);
    mlp_mfma_kernel<<<(NN + 127) / 128, 256, 0, stream>>>(x, W1t, b1, W2, b2,
                                                          logb0);

    const int E2B = (E2K + 255) / 256;

    hipMemsetAsync(cnt, 0, (size_t)NN * sizeof(int), stream);
    deg_pair_kernel<<<E2B, 256, 0, stream>>>(ei, cnt);
    scan_partial_kernel<<<NBLKS, 256, 0, stream>>>(cnt, partial);
    scan_tops_kernel<<<1, 256, 0, stream>>>(partial, tops);
    scan_write_kernel<<<NBLKS, 256, 0, stream>>>(cnt, tops, off);
    hipMemsetAsync(cnt, 0, (size_t)NN * sizeof(int), stream);
    pos_pair_kernel<<<E2B, 256, 0, stream>>>(ei, ew, off, cnt, perm_sw, rvp);

    const int MB = (EE + 511) / 512;   // 1563 blocks, 2 edges/thread
    const int AB = (NN + 31) / 32;     // 1563 blocks, 8 lanes/node
    uint4* msgs[2] = {msgA, msgB};
    float* bels[2] = {belA, belB};
    const float* bprev = logb0;
    for (int it = 0; it < KIT; ++it) {
        msg_kernel<<<MB, 256, 0, stream>>>(
            perm_sw, rvp, logH, msgs[(it + 1) & 1] /*prev*/, bprev,
            msgs[it & 1] /*next*/, it == 0 ? 1 : 0);
        agg_kernel<<<AB, 256, 0, stream>>>(
            logb0, off, msgs[it & 1], bels[it & 1], out,
            it == KIT - 1 ? 1 : 0);
        bprev = bels[it & 1];
    }
}

// Round 3
// 441.430 us; speedup vs baseline: 1.0569x; 1.0498x over previous
//
#include <hip/hip_runtime.h>
#include <hip/hip_bf16.h>
#include <hip/hip_fp16.h>
#include <math.h>

#define NN 50000
#define EE 800000
#define E2K 400000
#define DINK 512
#define DHK 128
#define CK 8
#define KIT 5
#define NBLKS 196  // ceil(NN/256)
#define EPT 4      // edges per thread in msg_kernel (software pipeline depth)

typedef __attribute__((ext_vector_type(8))) short short8;
typedef __attribute__((ext_vector_type(4))) float f32x4;

__device__ __forceinline__ unsigned short f2bf(float f) {
    union { float f; unsigned int u; } v;
    v.f = f;
    unsigned int u = v.u;
    unsigned int r = (u + 0x7FFFu + ((u >> 16) & 1u)) >> 16;  // RNE
    return (unsigned short)r;
}
__device__ __forceinline__ float bfu2f(unsigned int lo16) {
    union { unsigned int u; float f; } v;
    v.u = lo16 << 16;
    return v.f;
}

// merged prep: blocks 0..255 transpose W1 -> bf16 W1t; block 256 computes
// logH; blocks 257..452 zero cnt (replaces first hipMemsetAsync dispatch).
__global__ __launch_bounds__(256) void prep_kernel(
    const float* __restrict__ W1, const float* __restrict__ param,
    unsigned short* __restrict__ W1t, float* __restrict__ logH,
    int* __restrict__ cnt) {
    if (blockIdx.x < 256) {
        int idx = blockIdx.x * 256 + threadIdx.x;  // 65536
        int n = idx >> 9;
        int k = idx & 511;
        W1t[idx] = f2bf(W1[(size_t)k * DHK + n]);
    } else if (blockIdx.x == 256) {
        if (threadIdx.x < 64) {
            int t = threadIdx.x;
            int i = t >> 3, j = t & 7;
            float z = param[i * 8 + j] + param[j * 8 + i];
            logH[t] = fminf(z, 0.0f) - log1pf(expf(-fabsf(z)));
        }
    } else {
        int i = (blockIdx.x - 257) * 256 + threadIdx.x;
        if (i < NN) cnt[i] = 0;
    }
}

// MFMA MLP (R7-proven: 256 thr, 128 rows/block, VGPR ~100, ~70us) — verbatim.
__global__ __launch_bounds__(256) void mlp_mfma_kernel(
    const float* __restrict__ x, const unsigned short* __restrict__ W1t,
    const float* __restrict__ b1, const float* __restrict__ W2,
    const float* __restrict__ b2, float* __restrict__ logb0) {
    __shared__ unsigned short hs[128 * 136];
    __shared__ float W2s[128 * 8];
    __shared__ float b1s[128];
    __shared__ float b2s[8];

    const int tid = threadIdx.x;
    const int wave = tid >> 6;
    const int lane = tid & 63;
    const int q = lane >> 4;
    const int lm = lane & 15;
    const int wm = wave >> 1, wn = wave & 1;
    const int n0 = blockIdx.x * 128;

    if (tid < 128) b1s[tid] = b1[tid];
    if (tid < 8) b2s[tid] = b2[tid];
    {
        int i = tid * 4;
        *(float4*)&W2s[i] = *(const float4*)&W2[i];
    }
    __syncthreads();

    const float* xptr[4];
#pragma unroll
    for (int mt = 0; mt < 4; ++mt) {
        int r = n0 + wm * 64 + mt * 16 + lm;
        if (r > NN - 1) r = NN - 1;
        xptr[mt] = x + (size_t)r * DINK + q * 8;
    }
    const unsigned short* bptr[4];
#pragma unroll
    for (int nt = 0; nt < 4; ++nt) {
        int c = wn * 64 + nt * 16 + lm;
        bptr[nt] = W1t + (size_t)c * DINK + q * 8;
    }

    f32x4 acc[4][4];
#pragma unroll
    for (int mt = 0; mt < 4; ++mt)
#pragma unroll
        for (int nt = 0; nt < 4; ++nt) acc[mt][nt] = (f32x4){0.f, 0.f, 0.f, 0.f};

    float4 ar[4][2];
    short8 bc[4];
#pragma unroll
    for (int mt = 0; mt < 4; ++mt) {
        ar[mt][0] = *(const float4*)(xptr[mt]);
        ar[mt][1] = *(const float4*)(xptr[mt] + 4);
    }
#pragma unroll
    for (int nt = 0; nt < 4; ++nt) bc[nt] = *(const short8*)(bptr[nt]);

#pragma unroll
    for (int k0 = 32; k0 <= DINK; k0 += 32) {
        float4 ar2[4][2];
        short8 b2f[4];
        if (k0 < DINK) {
#pragma unroll
            for (int mt = 0; mt < 4; ++mt) {
                ar2[mt][0] = *(const float4*)(xptr[mt] + k0);
                ar2[mt][1] = *(const float4*)(xptr[mt] + k0 + 4);
            }
#pragma unroll
            for (int nt = 0; nt < 4; ++nt)
                b2f[nt] = *(const short8*)(bptr[nt] + k0);
        }
        short8 af[4];
#pragma unroll
        for (int mt = 0; mt < 4; ++mt) {
            union { short8 s; __hip_bfloat162 h[4]; } cv;
            cv.h[0] = __float22bfloat162_rn(make_float2(ar[mt][0].x, ar[mt][0].y));
            cv.h[1] = __float22bfloat162_rn(make_float2(ar[mt][0].z, ar[mt][0].w));
            cv.h[2] = __float22bfloat162_rn(make_float2(ar[mt][1].x, ar[mt][1].y));
            cv.h[3] = __float22bfloat162_rn(make_float2(ar[mt][1].z, ar[mt][1].w));
            af[mt] = cv.s;
        }
#pragma unroll
        for (int mt = 0; mt < 4; ++mt)
#pragma unroll
            for (int nt = 0; nt < 4; ++nt)
                acc[mt][nt] = __builtin_amdgcn_mfma_f32_16x16x32_bf16(
                    af[mt], bc[nt], acc[mt][nt], 0, 0, 0);
        if (k0 < DINK) {
#pragma unroll
            for (int mt = 0; mt < 4; ++mt) {
                ar[mt][0] = ar2[mt][0];
                ar[mt][1] = ar2[mt][1];
            }
#pragma unroll
            for (int nt = 0; nt < 4; ++nt) bc[nt] = b2f[nt];
        }
    }

#pragma unroll
    for (int nt = 0; nt < 4; ++nt) {
        int j = wn * 64 + nt * 16 + lm;
        float bj = b1s[j];
#pragma unroll
        for (int mt = 0; mt < 4; ++mt) {
            int rbase = wm * 64 + mt * 16 + q * 4;
#pragma unroll
            for (int r = 0; r < 4; ++r) {
                float h = fmaxf(acc[mt][nt][r] + bj, 0.0f);
                hs[(rbase + r) * 136 + j] = f2bf(h);
            }
        }
    }
    __syncthreads();

    int row = tid >> 1;
    int half = tid & 1;
    const unsigned short* hp = &hs[row * 136 + half * 64];
    float p[8] = {0.f, 0.f, 0.f, 0.f, 0.f, 0.f, 0.f, 0.f};
#pragma unroll
    for (int ch = 0; ch < 8; ++ch) {
        uint4 c4 = *(const uint4*)(hp + ch * 8);
        unsigned int uu[4] = {c4.x, c4.y, c4.z, c4.w};
#pragma unroll
        for (int p2 = 0; p2 < 4; ++p2) {
            float h0 = bfu2f(uu[p2] & 0xFFFFu);
            float h1 = bfu2f(uu[p2] >> 16);
            int j = half * 64 + ch * 8 + p2 * 2;
            const float* w0 = &W2s[j * 8];
            const float* w1 = &W2s[(j + 1) * 8];
#pragma unroll
            for (int c = 0; c < 8; ++c) p[c] = fmaf(h0, w0[c], p[c]);
#pragma unroll
            for (int c = 0; c < 8; ++c) p[c] = fmaf(h1, w1[c], p[c]);
        }
    }
#pragma unroll
    for (int c = 0; c < 8; ++c) p[c] += __shfl_xor(p[c], 1, 64);
    int grow = n0 + row;
    if (half == 0 && grow < NN) {
        float v[8];
        float mx = -1e30f;
#pragma unroll
        for (int c = 0; c < 8; ++c) {
            v[c] = p[c] + b2s[c];
            mx = fmaxf(mx, v[c]);
        }
        float s = 0.0f;
#pragma unroll
        for (int c = 0; c < 8; ++c) s += expf(v[c] - mx);
        float ln = mx + logf(s);
        float4* p0 = (float4*)&logb0[(size_t)grow * 8];
        p0[0] = make_float4(v[0] - ln, v[1] - ln, v[2] - ln, v[3] - ln);
        p0[1] = make_float4(v[4] - ln, v[5] - ln, v[6] - ln, v[7] - ln);
    }
}

// ---------------- CSR setup (paired: one thread per UNDIRECTED edge) --------

__global__ __launch_bounds__(256) void deg_pair_kernel(const int* __restrict__ ei,
                                                       int* __restrict__ cnt) {
    int e = blockIdx.x * 256 + threadIdx.x;
    if (e >= E2K) return;
    int s = ei[e];
    int d = ei[EE + e];
    atomicAdd(&cnt[d], 1);
    atomicAdd(&cnt[s], 1);
}

__global__ __launch_bounds__(256) void scan_partial_kernel(
    const int* __restrict__ cnt, int* __restrict__ partial) {
    __shared__ int sd[256];
    int t = threadIdx.x;
    int i = blockIdx.x * 256 + t;
    sd[t] = (i < NN) ? cnt[i] : 0;
    __syncthreads();
#pragma unroll
    for (int s = 128; s > 0; s >>= 1) {
        if (t < s) sd[t] += sd[t + s];
        __syncthreads();
    }
    if (t == 0) partial[blockIdx.x] = sd[0];
}

__global__ __launch_bounds__(256) void scan_tops_kernel(
    const int* __restrict__ partial, int* __restrict__ tops) {
    __shared__ int sd[256];
    int t = threadIdx.x;
    sd[t] = (t < NBLKS) ? partial[t] : 0;
    __syncthreads();
#pragma unroll
    for (int s = 1; s < 256; s <<= 1) {
        int a = sd[t];
        int b = (t >= s) ? sd[t - s] : 0;
        __syncthreads();
        sd[t] = a + b;
        __syncthreads();
    }
    if (t < NBLKS) tops[t] = (t > 0) ? sd[t - 1] : 0;
}

// also zeroes cnt after reading it (replaces second hipMemsetAsync dispatch)
__global__ __launch_bounds__(256) void scan_write_kernel(
    const int* __restrict__ cnt, const int* __restrict__ tops,
    int* __restrict__ off, int* __restrict__ cnt_z) {
    __shared__ int sd[256];
    int t = threadIdx.x;
    int i = blockIdx.x * 256 + t;
    int v = (i < NN) ? cnt[i] : 0;
    sd[t] = v;
    __syncthreads();
#pragma unroll
    for (int s = 1; s < 256; s <<= 1) {
        int a = sd[t];
        int b = (t >= s) ? sd[t - s] : 0;
        __syncthreads();
        sd[t] = a + b;
        __syncthreads();
    }
    if (i < NN) {
        off[i] = tops[blockIdx.x] + sd[t] - v;
        cnt_z[i] = 0;
    }
    if (i == NN - 1) off[NN] = EE;
}

// perm_sw=(src,wbits) int2; rvp = permuted index of reverse edge (int).
__global__ __launch_bounds__(256) void pos_pair_kernel(
    const int* __restrict__ ei, const float* __restrict__ ew,
    const int* __restrict__ off, int* __restrict__ cnt,
    int2* __restrict__ perm_sw, int* __restrict__ rvp) {
    int e = blockIdx.x * 256 + threadIdx.x;
    if (e >= E2K) return;
    int s = ei[e];
    int d = ei[EE + e];
    int wbits = __float_as_int(ew[e]);
    int pA = off[d] + atomicAdd(&cnt[d], 1);  // edge e: s->d
    int pB = off[s] + atomicAdd(&cnt[s], 1);  // edge e+E2: d->s
    int2 v;
    v.x = s; v.y = wbits; perm_sw[pA] = v;
    v.x = d;              perm_sw[pB] = v;
    rvp[pA] = pB;
    rvp[pB] = pA;
}

// ---------------- BP iteration: pipelined msg + unrolled agg ---------------
// msg_kernel: 4 edges/thread. Headers (contiguous) loaded up front; belief +
// reverse-message gathers for edge e+1 issued before computing edge e, so
// gather latency hides under the ~1000-cy exp/log block.
// Messages are written UNNORMALIZED (mg in [-4.5, 2.1]): a channel-uniform
// shift cancels exactly in the belief log-normalize and in bel-msg; also no
// max-subtraction needed (max_c1 xj >= -4.2 with normalized beliefs, so
// exp args <= ~4.6: f32-safe).
__global__ __launch_bounds__(256) void msg_kernel(
    const int2* __restrict__ perm_sw, const int* __restrict__ rvp,
    const float* __restrict__ logH, const uint4* __restrict__ msg_prev,
    const float* __restrict__ bel_prev, uint4* __restrict__ msg_next,
    int first) {
    __shared__ float lH[64];
    const int t = threadIdx.x;
    if (t < 64) lH[t] = logH[t];
    __syncthreads();

    const int base = blockIdx.x * (256 * EPT) + t;

    int jj[EPT];
    int2 sw[EPT];
    int rv[EPT];
#pragma unroll
    for (int e = 0; e < EPT; ++e) {
        int j = base + e * 256;
        jj[e] = j;
        int jc = (j < EE) ? j : (EE - 1);
        sw[e] = perm_sw[jc];
        rv[e] = rvp[jc];
    }

    // prologue: gathers for edge 0
    const float* pb0 = &bel_prev[(size_t)sw[0].x * 8];
    float4 ba = *(const float4*)pb0;
    float4 bb = *(const float4*)(pb0 + 4);
    uint4 mp = make_uint4(0, 0, 0, 0);
    if (!first) mp = msg_prev[rv[0]];

#pragma unroll
    for (int e = 0; e < EPT; ++e) {
        float4 nba = ba, nbb = bb;
        uint4 nmp = mp;
        if (e + 1 < EPT) {
            const float* pb = &bel_prev[(size_t)sw[e + 1].x * 8];
            nba = *(const float4*)pb;
            nbb = *(const float4*)(pb + 4);
            if (!first) nmp = msg_prev[rv[e + 1]];
        }

        float w = __int_as_float(sw[e].y);
        float xj[8];
        xj[0] = ba.x; xj[1] = ba.y; xj[2] = ba.z; xj[3] = ba.w;
        xj[4] = bb.x; xj[5] = bb.y; xj[6] = bb.z; xj[7] = bb.w;
        if (!first) {
            union { uint4 u; _Float16 h[8]; } cv;
            cv.u = mp;
#pragma unroll
            for (int k = 0; k < 8; ++k) xj[k] -= (float)cv.h[k];
        }
        float mg[8];
#pragma unroll
        for (int c2 = 0; c2 < 8; ++c2) {
            float ssum = 0.0f;
#pragma unroll
            for (int c1 = 0; c1 < 8; ++c1)
                ssum += __expf(fmaf(w, lH[c1 * 8 + c2], xj[c1]));
            mg[c2] = __logf(ssum);
        }
        union { uint4 u; _Float16 h[8]; } ov;
#pragma unroll
        for (int k = 0; k < 8; ++k) ov.h[k] = (_Float16)mg[k];
        if (jj[e] < EE) msg_next[jj[e]] = ov.u;

        ba = nba; bb = nbb; mp = nmp;
    }
}

__global__ __launch_bounds__(256) void agg_kernel(
    const float* __restrict__ logb0, const int* __restrict__ off,
    const uint4* __restrict__ msg, float* __restrict__ bel_next,
    float* __restrict__ out, int last) {
    const int t = threadIdx.x;
    const int n = blockIdx.x * 32 + (t >> 3);
    const int c = t & 7;
    if (n >= NN) return;
    float a = logb0[(size_t)n * 8 + c];
    const int j0 = off[n];
    const int j1 = off[n + 1];
    const _Float16* mh = (const _Float16*)msg;
    float s0 = 0.f, s1 = 0.f, s2 = 0.f, s3 = 0.f;
    int j = j0;
    for (; j + 4 <= j1; j += 4) {
        s0 += (float)mh[(size_t)(j + 0) * 8 + c];
        s1 += (float)mh[(size_t)(j + 1) * 8 + c];
        s2 += (float)mh[(size_t)(j + 2) * 8 + c];
        s3 += (float)mh[(size_t)(j + 3) * 8 + c];
    }
    for (; j < j1; ++j) s0 += (float)mh[(size_t)j * 8 + c];
    a += (s0 + s1) + (s2 + s3);
    float mx = a;
#pragma unroll
    for (int s = 1; s < 8; s <<= 1) mx = fmaxf(mx, __shfl_xor(mx, s, 8));
    float sum = __expf(a - mx);
#pragma unroll
    for (int s = 1; s < 8; s <<= 1) sum += __shfl_xor(sum, s, 8);
    float v = a - (mx + __logf(sum));
    if (last) out[(size_t)n * 8 + c] = v;
    else bel_next[(size_t)n * 8 + c] = v;
}

extern "C" void kernel_launch(void* const* d_in, const int* in_sizes, int n_in,
                              void* d_out, int out_size, void* d_ws, size_t ws_size,
                              hipStream_t stream) {
    const float* x = (const float*)d_in[0];
    const int* ei = (const int*)d_in[1];
    const float* ew = (const float*)d_in[2];
    const float* W1 = (const float*)d_in[4];
    const float* b1 = (const float*)d_in[5];
    const float* W2 = (const float*)d_in[6];
    const float* b2 = (const float*)d_in[7];
    const float* param = (const float*)d_in[8];
    float* out = (float*)d_out;

    float* wsf = (float*)d_ws;
    float* logH = wsf;                               // 64 f
    float* logb0 = logH + 64;                        // 400000 f
    uint4* msgA = (uint4*)(logb0 + (size_t)NN * 8);  // 12.8 MB
    uint4* msgB = msgA + EE;                         // 12.8 MB
    int* off = (int*)(msgB + EE);                    // padded to 50004 ints
    int2* perm_sw = (int2*)(off + 50004);            // 800000 int2
    int* rvp = (int*)(perm_sw + EE);                 // 800000 int
    unsigned short* W1t = (unsigned short*)(rvp + EE);  // 65536 bf16
    float* belA = (float*)(W1t + 65536);             // 400000 f (16B aligned)
    float* belB = belA + (size_t)NN * 8;             // 400000 f
    // setup-only scratch aliases msgA (first written by msg_kernel iter 0)
    int* cnt = (int*)msgA;                           // 50000
    int* partial = cnt + NN;                         // 196
    int* tops = partial + NBLKS;                     // 196

    prep_kernel<<<257 + NBLKS, 256, 0, stream>>>(W1, param, W1t, logH, cnt);
    mlp_mfma_kernel<<<(NN + 127) / 128, 256, 0, stream>>>(x, W1t, b1, W2, b2,
                                                          logb0);

    const int E2B = (E2K + 255) / 256;

    deg_pair_kernel<<<E2B, 256, 0, stream>>>(ei, cnt);
    scan_partial_kernel<<<NBLKS, 256, 0, stream>>>(cnt, partial);
    scan_tops_kernel<<<1, 256, 0, stream>>>(partial, tops);
    scan_write_kernel<<<NBLKS, 256, 0, stream>>>(cnt, tops, off, cnt);
    pos_pair_kernel<<<E2B, 256, 0, stream>>>(ei, ew, off, cnt, perm_sw, rvp);

    const int MB = (EE + 256 * EPT - 1) / (256 * EPT);  // 782 blocks
    const int AB = (NN + 31) / 32;                      // 1563 blocks
    uint4* msgs[2] = {msgA, msgB};
    float* bels[2] = {belA, belB};
    const float* bprev = logb0;
    for (int it = 0; it < KIT; ++it) {
        msg_kernel<<<MB, 256, 0, stream>>>(
            perm_sw, rvp, logH, msgs[(it + 1) & 1] /*prev*/, bprev,
            msgs[it & 1] /*next*/, it == 0 ? 1 : 0);
        agg_kernel<<<AB, 256, 0, stream>>>(
            logb0, off, msgs[it & 1], bels[it & 1], out,
            it == KIT - 1 ? 1 : 0);
        bprev = bels[it & 1];
    }
}